// Round 1
// baseline (496.482 us; speedup 1.0000x reference)
//
#include <hip/hip_runtime.h>
#include <stdint.h>

typedef short s16x8 __attribute__((ext_vector_type(8)));
typedef float f32x4 __attribute__((ext_vector_type(4)));

#define MFMA16(a, b, c) __builtin_amdgcn_mfma_f32_16x16x32_bf16((a), (b), (c), 0, 0, 0)

__device__ __forceinline__ ushort f2b(float f) {
  union { float f; uint32_t u; } x; x.f = f;
  uint32_t r = x.u + 0x7fffu + ((x.u >> 16) & 1u);
  return (ushort)(r >> 16);
}
__device__ __forceinline__ float b2f(ushort s) {
  union { uint32_t u; float f; } x; x.u = ((uint32_t)s) << 16;
  return x.f;
}

__global__ __launch_bounds__(256) void cast_f32_bf16(const float* __restrict__ src,
                                                     ushort* __restrict__ dst, int n) {
  int i = (blockIdx.x * 256 + threadIdx.x) * 4;
  if (i + 4 <= n) {
    float4 v = *(const float4*)(src + i);
    ushort4 o; o.x = f2b(v.x); o.y = f2b(v.y); o.z = f2b(v.z); o.w = f2b(v.w);
    *(ushort4*)(dst + i) = o;
  }
}

__device__ __forceinline__ void gload16(const void* g, void* l) {
  __builtin_amdgcn_global_load_lds((const __attribute__((address_space(1))) void*)g,
                                   (__attribute__((address_space(3))) void*)l, 16, 0, 0);
}

// ---------------- QKV GEMM: C[8192,3072] = Xbf16 @ Wbf16^T, epilogue splits heads
// m97 structure: 128x128 tile, BK=32, global_load_lds width 16, 16x16x32 bf16 MFMA.
__global__ __launch_bounds__(256) void qkv_gemm(
    const ushort* __restrict__ hb, const ushort* __restrict__ wb,
    const float* __restrict__ bq, const float* __restrict__ bk, const float* __restrict__ bv,
    ushort* __restrict__ qb, ushort* __restrict__ kb, ushort* __restrict__ vt) {
  __shared__ ushort As[128 * 32];
  __shared__ ushort Bs[128 * 32];
  const int tid = threadIdx.x;
  const int w = tid >> 6, lane = tid & 63, quad = lane >> 4, l16 = lane & 15;
  const int m0 = blockIdx.y * 128, n0 = blockIdx.x * 128;

  const int srow = w * 32 + (lane >> 2);
  const int scol = (lane & 3) * 8;
  const ushort* ga = hb + (size_t)(m0 + srow) * 1024 + scol;
  const ushort* gw = wb + (size_t)(n0 + srow) * 1024 + scol;
  ushort* lA0 = As + (w * 32) * 32;
  ushort* lA1 = As + (w * 32 + 16) * 32;
  ushort* lB0 = Bs + (w * 32) * 32;
  ushort* lB1 = Bs + (w * 32 + 16) * 32;

  f32x4 acc[4][4];
#pragma unroll
  for (int mt = 0; mt < 4; ++mt)
#pragma unroll
    for (int nt = 0; nt < 4; ++nt) acc[mt][nt] = (f32x4){0.f, 0.f, 0.f, 0.f};

  const int wm = (w >> 1) * 64, wn = (w & 1) * 64;

  for (int k0 = 0; k0 < 1024; k0 += 32) {
    gload16(ga + k0, lA0);
    gload16(ga + k0 + 16 * 1024, lA1);
    gload16(gw + k0, lB0);
    gload16(gw + k0 + 16 * 1024, lB1);
    __syncthreads();
    s16x8 af[4], bfr[4];
#pragma unroll
    for (int mt = 0; mt < 4; ++mt)
      af[mt] = *(const s16x8*)(As + (wm + 16 * mt + l16) * 32 + quad * 8);
#pragma unroll
    for (int nt = 0; nt < 4; ++nt)
      bfr[nt] = *(const s16x8*)(Bs + (wn + 16 * nt + l16) * 32 + quad * 8);
#pragma unroll
    for (int mt = 0; mt < 4; ++mt)
#pragma unroll
      for (int nt = 0; nt < 4; ++nt)
        acc[mt][nt] = MFMA16(af[mt], bfr[nt], acc[mt][nt]);
    __syncthreads();
  }

  // epilogue: n<1024 -> q, <2048 -> k, else v (stored transposed [bh,d,l])
  const int mat = n0 >> 10;                     // uniform per block (8 n-blocks per matrix)
  const float* bias = (mat == 0) ? bq : ((mat == 1) ? bk : bv);
  const int b = m0 >> 10;                       // uniform per block
#pragma unroll
  for (int mt = 0; mt < 4; ++mt) {
    int mbase = m0 + wm + 16 * mt + 4 * quad;
#pragma unroll
    for (int nt = 0; nt < 4; ++nt) {
      int n = n0 + wn + 16 * nt + l16;
      int o = n & 1023; int hh = o >> 6; int d = o & 63;
      float bsv = bias[o];
#pragma unroll
      for (int reg = 0; reg < 4; ++reg) {
        int l = (mbase + reg) & 1023;
        ushort bx = f2b(acc[mt][nt][reg] + bsv);
        if (mat == 0)      qb[(((size_t)(b * 16 + hh)) * 1024 + l) * 64 + d] = bx;
        else if (mat == 1) kb[(((size_t)(b * 16 + hh)) * 1024 + l) * 64 + d] = bx;
        else               vt[(((size_t)(b * 16 + hh)) * 64 + d) * 1024 + l] = bx;
      }
    }
  }
}

// ---------------- Flash attention with relative_key_query bias
// block = 4 waves; wave w owns q-rows [16w,16w+16) of a 64-row Q tile.
// LDS (ushort units): PS(=QS) 64x72 @0, KS 64x72 @4608, VTS 64x72 @9216,
//                     ES 128x72 @13824, SE 128x68 @23040.  Total 63488 B.
#define ATT_PS  0
#define ATT_KS  4608
#define ATT_VTS 9216
#define ATT_ES  13824
#define ATT_SE  23040

__global__ __launch_bounds__(256) void attn_kernel(
    const ushort* __restrict__ qb, const ushort* __restrict__ kb,
    const ushort* __restrict__ vt, const ushort* __restrict__ eb,
    const float* __restrict__ mask, float* __restrict__ out) {
  __shared__ __align__(16) ushort sm[31744];
  const int tid = threadIdx.x;
  const int w = tid >> 6, lane = tid & 63, quad = lane >> 4, l16 = lane & 15;
  const int bh = blockIdx.y, b = bh >> 4, h = bh & 15;
  const int l0 = blockIdx.x * 64;

  // stage Q tile into PS region (row l-rel, col d; stride 72)
#pragma unroll
  for (int pass = 0; pass < 2; ++pass) {
    int idx = tid * 8 + pass * 2048;
    int row = idx >> 6, col = idx & 63;
    uint4 v = *(const uint4*)(qb + ((size_t)bh * 1024 + l0 + row) * 64 + col);
    *(uint4*)(sm + ATT_PS + row * 72 + col) = v;
  }
  __syncthreads();
  // hoist Q A-fragments (loop-invariant); PS region is then reused for P
  s16x8 aq0 = *(const s16x8*)(sm + ATT_PS + (w * 16 + l16) * 72 + quad * 8);
  s16x8 aq1 = *(const s16x8*)(sm + ATT_PS + (w * 16 + l16) * 72 + 32 + quad * 8);

  float m_run[4], l_run[4];
  f32x4 o_acc[4];
#pragma unroll
  for (int r = 0; r < 4; ++r) { m_run[r] = -1e30f; l_run[r] = 0.f; }
#pragma unroll
  for (int nt = 0; nt < 4; ++nt) o_acc[nt] = (f32x4){0.f, 0.f, 0.f, 0.f};

  const float LOG2E = 1.44269504088896f;
  const float SC = 0.125f * LOG2E;   // /sqrt(64), folded with base-2 exp

  for (int r0 = 0; r0 < 1024; r0 += 64) {
    __syncthreads();  // A: previous iteration's LDS readers done
    // stage K [r,d] and V^T [d,r]
#pragma unroll
    for (int pass = 0; pass < 2; ++pass) {
      int idx = tid * 8 + pass * 2048;
      int row = idx >> 6, col = idx & 63;
      uint4 kv = *(const uint4*)(kb + ((size_t)bh * 1024 + r0 + row) * 64 + col);
      *(uint4*)(sm + ATT_KS + row * 72 + col) = kv;
      uint4 vv = *(const uint4*)(vt + ((size_t)bh * 64 + row) * 1024 + r0 + col);
      *(uint4*)(sm + ATT_VTS + row * 72 + col) = vv;
    }
    // stage E band: rows t0..t0+127 (row 127 is pad, clamped)
    const int t0 = l0 - r0 + 960;
#pragma unroll
    for (int pass = 0; pass < 4; ++pass) {
      int idx = tid * 8 + pass * 2048;
      int row = idx >> 6, col = idx & 63;
      int t = t0 + row; if (t > 2046) t = 2046;
      uint4 ev = *(const uint4*)(eb + (size_t)t * 64 + col);
      *(uint4*)(sm + ATT_ES + row * 72 + col) = ev;
    }
    __syncthreads();  // B

    // S = Q K^T  (k=64 via two chained MFMAs)
    f32x4 s[4];
#pragma unroll
    for (int nt = 0; nt < 4; ++nt) {
      s16x8 bk0 = *(const s16x8*)(sm + ATT_KS + (16 * nt + l16) * 72 + quad * 8);
      s16x8 bk1 = *(const s16x8*)(sm + ATT_KS + (16 * nt + l16) * 72 + 32 + quad * 8);
      f32x4 z = (f32x4){0.f, 0.f, 0.f, 0.f};
      z = MFMA16(aq0, bk0, z);
      z = MFMA16(aq1, bk1, z);
      s[nt] = z;
    }

    // phase A: SE := Q @ E^T, stored transposed [j][l] (bf16, packed b64 writes)
#pragma unroll
    for (int nt = 0; nt < 8; ++nt) {
      s16x8 be0 = *(const s16x8*)(sm + ATT_ES + (16 * nt + l16) * 72 + quad * 8);
      s16x8 be1 = *(const s16x8*)(sm + ATT_ES + (16 * nt + l16) * 72 + 32 + quad * 8);
      f32x4 d1 = (f32x4){0.f, 0.f, 0.f, 0.f};
      d1 = MFMA16(aq0, be0, d1);
      d1 = MFMA16(aq1, be1, d1);
      ushort4 pk; pk.x = f2b(d1[0]); pk.y = f2b(d1[1]); pk.z = f2b(d1[2]); pk.w = f2b(d1[3]);
      *(ushort4*)(sm + ATT_SE + (16 * nt + l16) * 68 + (w * 16 + 4 * quad)) = pk;
    }
    // bias1 reads are wave-self data (own l columns): in-wave lgkmcnt ordering suffices
    float zv[4][4];
#pragma unroll
    for (int nt = 0; nt < 4; ++nt) {
      int rrel = 16 * nt + l16;
#pragma unroll
      for (int reg = 0; reg < 4; ++reg) {
        int lrel = w * 16 + 4 * quad + reg;
        int jj = lrel - rrel + 63;
        zv[nt][reg] = s[nt][reg] + b2f(sm[ATT_SE + jj * 68 + lrel]);
      }
    }
    // phase B: SE := K @ E^T, transposed [j][r] (each wave overwrites its own columns)
    s16x8 ak0 = *(const s16x8*)(sm + ATT_KS + (w * 16 + l16) * 72 + quad * 8);
    s16x8 ak1 = *(const s16x8*)(sm + ATT_KS + (w * 16 + l16) * 72 + 32 + quad * 8);
#pragma unroll
    for (int nt = 0; nt < 8; ++nt) {
      s16x8 be0 = *(const s16x8*)(sm + ATT_ES + (16 * nt + l16) * 72 + quad * 8);
      s16x8 be1 = *(const s16x8*)(sm + ATT_ES + (16 * nt + l16) * 72 + 32 + quad * 8);
      f32x4 d2 = (f32x4){0.f, 0.f, 0.f, 0.f};
      d2 = MFMA16(ak0, be0, d2);
      d2 = MFMA16(ak1, be1, d2);
      ushort4 pk; pk.x = f2b(d2[0]); pk.y = f2b(d2[1]); pk.z = f2b(d2[2]); pk.w = f2b(d2[3]);
      *(ushort4*)(sm + ATT_SE + (16 * nt + l16) * 68 + (w * 16 + 4 * quad)) = pk;
    }
    __syncthreads();  // C: bias2 (K-side) reads are cross-wave

    // logits (base-2), online softmax
    float mloc[4] = {-1e30f, -1e30f, -1e30f, -1e30f};
#pragma unroll
    for (int nt = 0; nt < 4; ++nt) {
      int rrel = 16 * nt + l16;
      float mk = mask[b * 1024 + r0 + rrel] * LOG2E;
#pragma unroll
      for (int reg = 0; reg < 4; ++reg) {
        int lrel = w * 16 + 4 * quad + reg;
        int jj = lrel - rrel + 63;
        float z2 = (zv[nt][reg] + b2f(sm[ATT_SE + jj * 68 + rrel])) * SC + mk;
        zv[nt][reg] = z2;
        mloc[reg] = fmaxf(mloc[reg], z2);
      }
    }
#pragma unroll
    for (int off = 1; off < 16; off <<= 1)
#pragma unroll
      for (int reg = 0; reg < 4; ++reg)
        mloc[reg] = fmaxf(mloc[reg], __shfl_xor(mloc[reg], off));
    float scale[4], rsum[4];
#pragma unroll
    for (int reg = 0; reg < 4; ++reg) {
      float mn = fmaxf(m_run[reg], mloc[reg]);
      scale[reg] = exp2f(m_run[reg] - mn);
      m_run[reg] = mn;
      rsum[reg] = 0.f;
    }
#pragma unroll
    for (int nt = 0; nt < 4; ++nt)
#pragma unroll
      for (int reg = 0; reg < 4; ++reg) {
        float p = exp2f(zv[nt][reg] - m_run[reg]);
        zv[nt][reg] = p;
        rsum[reg] += p;
      }
#pragma unroll
    for (int off = 1; off < 16; off <<= 1)
#pragma unroll
      for (int reg = 0; reg < 4; ++reg)
        rsum[reg] += __shfl_xor(rsum[reg], off);
#pragma unroll
    for (int reg = 0; reg < 4; ++reg) l_run[reg] = l_run[reg] * scale[reg] + rsum[reg];
#pragma unroll
    for (int nt = 0; nt < 4; ++nt)
#pragma unroll
      for (int reg = 0; reg < 4; ++reg) o_acc[nt][reg] *= scale[reg];

    // P -> LDS (C-layout scatter into [l][r]); rows are wave-private
#pragma unroll
    for (int nt = 0; nt < 4; ++nt)
#pragma unroll
      for (int reg = 0; reg < 4; ++reg) {
        int lrel = w * 16 + 4 * quad + reg;
        int rrel = 16 * nt + l16;
        sm[ATT_PS + lrel * 72 + rrel] = f2b(zv[nt][reg]);
      }
    __syncthreads();  // E: P visible (and cheap insurance on LDS ordering)

    // O += P @ V
#pragma unroll
    for (int kk = 0; kk < 2; ++kk) {
      s16x8 ap = *(const s16x8*)(sm + ATT_PS + (w * 16 + l16) * 72 + kk * 32 + quad * 8);
#pragma unroll
      for (int nt = 0; nt < 4; ++nt) {
        s16x8 bv_ = *(const s16x8*)(sm + ATT_VTS + (16 * nt + l16) * 72 + kk * 32 + quad * 8);
        o_acc[nt] = MFMA16(ap, bv_, o_acc[nt]);
      }
    }
  }

  // epilogue: out[b, l, h*64+d] = O / l_run
#pragma unroll
  for (int nt = 0; nt < 4; ++nt)
#pragma unroll
    for (int reg = 0; reg < 4; ++reg) {
      int l = l0 + w * 16 + 4 * quad + reg;
      int d = 16 * nt + l16;
      out[((size_t)(b * 1024 + l)) * 1024 + h * 64 + d] = o_acc[nt][reg] / l_run[reg];
    }
}

// ---------------- host launch
extern "C" void kernel_launch(void* const* d_in, const int* in_sizes, int n_in,
                              void* d_out, int out_size, void* d_ws, size_t ws_size,
                              hipStream_t stream) {
  const float* hidden = (const float*)d_in[0];
  const float* mask   = (const float*)d_in[1];
  const float* Wq     = (const float*)d_in[2];
  const float* bq     = (const float*)d_in[3];
  const float* Wk     = (const float*)d_in[4];
  const float* bk     = (const float*)d_in[5];
  const float* Wv     = (const float*)d_in[6];
  const float* bv     = (const float*)d_in[7];
  const float* dist   = (const float*)d_in[8];
  float* out = (float*)d_out;

  // workspace layout (ushort units): qb, kb, vt(16MB ea), hb 16MB, wb 6MB, eb 0.25MB
  ushort* ws = (ushort*)d_ws;
  ushort* qb = ws;
  ushort* kb = ws + 8388608;
  ushort* vt = ws + 16777216;
  ushort* hb = ws + 25165824;
  ushort* wb = ws + 33554432;
  ushort* eb = ws + 36700160;

  cast_f32_bf16<<<8192, 256, 0, stream>>>(hidden, hb, 8388608);
  cast_f32_bf16<<<1024, 256, 0, stream>>>(Wq, wb, 1048576);
  cast_f32_bf16<<<1024, 256, 0, stream>>>(Wk, wb + 1048576, 1048576);
  cast_f32_bf16<<<1024, 256, 0, stream>>>(Wv, wb + 2097152, 1048576);
  cast_f32_bf16<<<128, 256, 0, stream>>>(dist, eb, 131008);

  qkv_gemm<<<dim3(24, 64), 256, 0, stream>>>(hb, wb, bq, bk, bv, qb, kb, vt);
  attn_kernel<<<dim3(16, 128), 256, 0, stream>>>(qb, kb, vt, eb, mask, out);
}